// Round 9
// baseline (1108.437 us; speedup 1.0000x reference)
//
#include <hip/hip_runtime.h>
#include <hip/hip_fp16.h>

#define F_IN 1433
#define KPAD 1472      // 23*64, zero-padded K
#define BCAP 96        // bucket capacity; deg ~ Poisson(32), P(>96) ~ 1e-18

// edge_index int32: src = ei[0:E], dst = ei[E:2E]

// LDS W1 layout: halfword index of (k,c) = k*16 + (k>>2)*8 + c (144B per 4-row group)
__device__ __forceinline__ int widx(int k, int c) { return (k << 4) + ((k >> 2) << 3) + c; }

__device__ __forceinline__ void gridbar(int* bar, int target) {
    __syncthreads();
    if (threadIdx.x == 0) {
        __hip_atomic_fetch_add(bar, 1, __ATOMIC_RELEASE, __HIP_MEMORY_SCOPE_AGENT);
        while (__hip_atomic_load(bar, __ATOMIC_ACQUIRE, __HIP_MEMORY_SCOPE_AGENT) < target)
            __builtin_amdgcn_s_sleep(2);
    }
    __syncthreads();
}

// ---------------- node 1: g1 = x @ W1 (RAW, no dinv) + zero bar/cnt ----------------
// 2 rows x 16 cols per wave (32 accs) -> no VGPR spill; dinv applied in aggA.
__global__ __launch_bounds__(512, 4) void k_gemm(
    const float* __restrict__ x, const float* __restrict__ W1,
    int* __restrict__ zbuf, int zlen,      // bar + cnt, zeroed for node 2
    float* __restrict__ g1, int N)
{
    // grid-stride zero of bar+cnt (visible to node 2 via node boundary)
    for (int i = blockIdx.x * 512 + threadIdx.x; i < zlen; i += gridDim.x * 512)
        zbuf[i] = 0;

    __shared__ __half wlds[KPAD * 16 + (KPAD / 4) * 8];   // 52992 B
    int tid = threadIdx.x;
    for (int i = tid; i < KPAD * 16; i += 512) {
        int k = i >> 4, c = i & 15;
        float v = (i < F_IN * 16) ? W1[i] : 0.0f;
        wlds[widx(k, c)] = __float2half(v);
    }
    __syncthreads();

    int wave = tid >> 6, lane = tid & 63;
    int row0 = (blockIdx.x * 8 + wave) * 2;
    if (row0 >= N) return;

    const float* xr0 = x + (size_t)row0 * F_IN;
    const float* xr1 = (row0 + 1 < N) ? xr0 + F_IN : xr0;

    float v[32];   // acc[r*16+c], r in {0,1}
    #pragma unroll
    for (int a = 0; a < 32; ++a) v[a] = 0.0f;

    struct __attribute__((packed, aligned(4))) f4u { float f[4]; };

    // vector phase: k < 1280
    for (int j = 0; j < 5; ++j) {
        int k4 = j * 256 + lane * 4;
        f4u a0 = *(const f4u*)&xr0[k4];
        f4u a1 = *(const f4u*)&xr1[k4];
        #pragma unroll
        for (int i = 0; i < 4; ++i) {
            int hb = widx(k4 + i, 0);
            float4 wa = *(const float4*)&wlds[hb];
            float4 wb = *(const float4*)&wlds[hb + 8];
            const __half2* ha = (const __half2*)&wa;
            const __half2* hc = (const __half2*)&wb;
            float xv0 = a0.f[i], xv1 = a1.f[i];
            #pragma unroll
            for (int p = 0; p < 4; ++p) {
                float w0 = __low2float(ha[p]), w1 = __high2float(ha[p]);
                float w2 = __low2float(hc[p]), w3 = __high2float(hc[p]);
                v[2 * p]          = fmaf(xv0, w0, v[2 * p]);
                v[2 * p + 1]      = fmaf(xv0, w1, v[2 * p + 1]);
                v[2 * p + 8]      = fmaf(xv0, w2, v[2 * p + 8]);
                v[2 * p + 9]      = fmaf(xv0, w3, v[2 * p + 9]);
                v[16 + 2 * p]     = fmaf(xv1, w0, v[16 + 2 * p]);
                v[16 + 2 * p + 1] = fmaf(xv1, w1, v[16 + 2 * p + 1]);
                v[16 + 2 * p + 8] = fmaf(xv1, w2, v[16 + 2 * p + 8]);
                v[16 + 2 * p + 9] = fmaf(xv1, w3, v[16 + 2 * p + 9]);
            }
        }
    }

    // scalar tail: k in [1280, 1433)
    for (int jj = 0; jj < 3; ++jj) {
        int k = 1280 + jj * 64 + lane;
        bool ok = k < F_IN;
        float xv0 = ok ? xr0[k] : 0.0f;
        float xv1 = ok ? xr1[k] : 0.0f;
        #pragma unroll
        for (int p = 0; p < 8; ++p) {
            __half2 h2 = *(const __half2*)&wlds[widx(k, 2 * p)];
            float wx = __low2float(h2), wy = __high2float(h2);
            v[2 * p]          += xv0 * wx;
            v[2 * p + 1]      += xv0 * wy;
            v[16 + 2 * p]     += xv1 * wx;
            v[16 + 2 * p + 1] += xv1 * wy;
        }
    }

    // butterfly: 5 rounds -> lane L holds acc (L&31) summed within its 32-lane half
    #pragma unroll
    for (int st = 0; st < 5; ++st) {
        int n = 16 >> st;
        bool up = (lane >> st) & 1;
        #pragma unroll
        for (int i = 0; i < n; ++i) {
            float a0 = v[2 * i], a1 = v[2 * i + 1];
            float keep = up ? a1 : a0;
            float send = up ? a0 : a1;
            v[i] = keep + __shfl_xor(send, 1 << st, 64);
        }
    }
    v[0] += __shfl_xor(v[0], 32, 64);   // combine halves

    if (lane < 32) {
        int r = lane >> 4, c = lane & 15;
        int row = row0 + r;
        if (row < N) g1[row * 16 + c] = v[0];   // RAW
    }
}

// ---------------- node 2: scatter -> bar -> aggA' -> bar -> aggB -> bar -> aggC ----------------
__global__ __launch_bounds__(256) void k_graph(
    const int* __restrict__ ei, int* __restrict__ cnt, int* __restrict__ bucket,
    const float* __restrict__ g1,
    const float* __restrict__ W2, const float* __restrict__ b1,
    const float* __restrict__ W3, const float* __restrict__ b2,
    const float* __restrict__ b3,
    float* __restrict__ s2, float* __restrict__ s3, float* __restrict__ out,
    int* bar, int N, int E)
{
    __shared__ float w2s[256], w3s[112], b1s[16], b2s[16], b3s[8];
    int tid = threadIdx.x;
    w2s[tid] = W2[tid];
    if (tid < 112) w3s[tid] = W3[tid];
    if (tid < 16)  b1s[tid] = b1[tid];
    if (tid < 16)  b2s[tid] = b2[tid];
    if (tid < 8)   b3s[tid] = (tid < 7) ? b3[tid] : 0.0f;
    __syncthreads();

    int G = gridDim.x;

    // ---- phase S: histogram + bucket scatter ----
    for (int e = blockIdx.x * 256 + tid; e < E; e += G * 256) {
        int s = ei[e], d = ei[E + e];
        if ((unsigned)s < (unsigned)N && (unsigned)d < (unsigned)N) {
            int slot = atomicAdd(&cnt[d], 1);
            if (slot < BCAP) bucket[(size_t)d * BCAP + slot] = s;
        }
    }

    gridbar(bar, G);

    int wave = tid >> 6, lane = tid & 63;
    int wgid = blockIdx.x * 4 + wave, wtot = G * 4;
    int g = lane >> 4, c = lane & 15;

    // ---- phase A: conv1-agg (dinv[src] folded per edge) + b1 + relu + @W2 + dinv ----
    for (int dst = wgid; dst < N; dst += wtot) {
        int cd = cnt[dst];
        int deg = min(cd, BCAP);
        float di = rsqrtf((float)cd + 1.0f);
        const int* bk = bucket + (size_t)dst * BCAP;
        int e0 = (lane < deg)      ? bk[lane]      : 0;
        int e1 = (64 + lane < deg) ? bk[64 + lane] : 0;

        float acc = (g == 0) ? di * g1[dst * 16 + c] : 0.0f;   // self-loop
        for (int base = 0; base < deg; base += 16) {
            int j0 = base + g, j1 = j0 + 4, j2 = j0 + 8, j3 = j0 + 12;
            int sa0 = __shfl(e0, j0 & 63, 64), sb0 = __shfl(e1, j0 & 63, 64);
            int sa1 = __shfl(e0, j1 & 63, 64), sb1 = __shfl(e1, j1 & 63, 64);
            int sa2 = __shfl(e0, j2 & 63, 64), sb2 = __shfl(e1, j2 & 63, 64);
            int sa3 = __shfl(e0, j3 & 63, 64), sb3 = __shfl(e1, j3 & 63, 64);
            int s0 = (j0 < 64) ? sa0 : sb0;
            int s1 = (j1 < 64) ? sa1 : sb1;
            int s2i = (j2 < 64) ? sa2 : sb2;
            int s3i = (j3 < 64) ? sa3 : sb3;
            float v0 = 0.0f, v1 = 0.0f, v2 = 0.0f, v3 = 0.0f;
            if (j0 < deg) v0 = rsqrtf((float)cnt[s0] + 1.0f)  * g1[s0 * 16 + c];
            if (j1 < deg) v1 = rsqrtf((float)cnt[s1] + 1.0f)  * g1[s1 * 16 + c];
            if (j2 < deg) v2 = rsqrtf((float)cnt[s2i] + 1.0f) * g1[s2i * 16 + c];
            if (j3 < deg) v3 = rsqrtf((float)cnt[s3i] + 1.0f) * g1[s3i * 16 + c];
            acc += (v0 + v1) + (v2 + v3);
        }
        acc += __shfl_xor(acc, 16, 64);
        acc += __shfl_xor(acc, 32, 64);

        float h = fmaxf(fmaf(di, acc, b1s[c]), 0.0f);
        float t = 0.0f;
        #pragma unroll
        for (int k = 0; k < 16; ++k)
            t = fmaf(__shfl(h, k, 16), w2s[k * 16 + c], t);
        if (lane < 16) s2[dst * 16 + c] = di * t;
    }

    gridbar(bar, 2 * G);

    // ---- phase B: conv2-agg + b2 + relu + @W3 + dinv ----
    for (int dst = wgid; dst < N; dst += wtot) {
        int cd = cnt[dst];
        int deg = min(cd, BCAP);
        float di = rsqrtf((float)cd + 1.0f);
        const int* bk = bucket + (size_t)dst * BCAP;
        int e0 = (lane < deg)      ? bk[lane]      : 0;
        int e1 = (64 + lane < deg) ? bk[64 + lane] : 0;

        float acc = (g == 0) ? s2[dst * 16 + c] : 0.0f;
        for (int base = 0; base < deg; base += 16) {
            int j0 = base + g, j1 = j0 + 4, j2 = j0 + 8, j3 = j0 + 12;
            int sa0 = __shfl(e0, j0 & 63, 64), sb0 = __shfl(e1, j0 & 63, 64);
            int sa1 = __shfl(e0, j1 & 63, 64), sb1 = __shfl(e1, j1 & 63, 64);
            int sa2 = __shfl(e0, j2 & 63, 64), sb2 = __shfl(e1, j2 & 63, 64);
            int sa3 = __shfl(e0, j3 & 63, 64), sb3 = __shfl(e1, j3 & 63, 64);
            int s0 = (j0 < 64) ? sa0 : sb0;
            int s1 = (j1 < 64) ? sa1 : sb1;
            int s2i = (j2 < 64) ? sa2 : sb2;
            int s3i = (j3 < 64) ? sa3 : sb3;
            float v0 = (j0 < deg) ? s2[s0 * 16 + c]  : 0.0f;
            float v1 = (j1 < deg) ? s2[s1 * 16 + c]  : 0.0f;
            float v2 = (j2 < deg) ? s2[s2i * 16 + c] : 0.0f;
            float v3 = (j3 < deg) ? s2[s3i * 16 + c] : 0.0f;
            acc += (v0 + v1) + (v2 + v3);
        }
        acc += __shfl_xor(acc, 16, 64);
        acc += __shfl_xor(acc, 32, 64);

        float h = fmaxf(fmaf(di, acc, b2s[c]), 0.0f);
        int cc = (c < 7) ? c : 0;
        float t = 0.0f;
        #pragma unroll
        for (int k = 0; k < 16; ++k)
            t = fmaf(__shfl(h, k, 16), w3s[k * 7 + cc], t);
        if (lane < 7) s3[dst * 7 + c] = di * t;
    }

    gridbar(bar, 3 * G);

    // ---- phase C: conv3-agg + b3 + log_softmax ----
    int g8 = lane >> 3, c8 = lane & 7;
    bool c7 = (c8 < 7);
    int cc8 = c7 ? c8 : 0;
    for (int dst = wgid; dst < N; dst += wtot) {
        int cd = cnt[dst];
        int deg = min(cd, BCAP);
        float di = rsqrtf((float)cd + 1.0f);
        const int* bk = bucket + (size_t)dst * BCAP;
        int e0 = (lane < deg)      ? bk[lane]      : 0;
        int e1 = (64 + lane < deg) ? bk[64 + lane] : 0;

        float acc = (g8 == 0 && c7) ? s3[dst * 7 + c8] : 0.0f;
        for (int base = 0; base < deg; base += 32) {
            int j0 = base + g8, j1 = j0 + 8, j2 = j0 + 16, j3 = j0 + 24;
            int sa0 = __shfl(e0, j0 & 63, 64), sb0 = __shfl(e1, j0 & 63, 64);
            int sa1 = __shfl(e0, j1 & 63, 64), sb1 = __shfl(e1, j1 & 63, 64);
            int sa2 = __shfl(e0, j2 & 63, 64), sb2 = __shfl(e1, j2 & 63, 64);
            int sa3 = __shfl(e0, j3 & 63, 64), sb3 = __shfl(e1, j3 & 63, 64);
            int s0 = (j0 < 64) ? sa0 : sb0;
            int s1 = (j1 < 64) ? sa1 : sb1;
            int s2i = (j2 < 64) ? sa2 : sb2;
            int s3i = (j3 < 64) ? sa3 : sb3;
            float v0 = (j0 < deg && c7) ? s3[s0 * 7 + cc8]  : 0.0f;
            float v1 = (j1 < deg && c7) ? s3[s1 * 7 + cc8]  : 0.0f;
            float v2 = (j2 < deg && c7) ? s3[s2i * 7 + cc8] : 0.0f;
            float v3 = (j3 < deg && c7) ? s3[s3i * 7 + cc8] : 0.0f;
            acc += (v0 + v1) + (v2 + v3);
        }
        acc += __shfl_xor(acc, 8, 64);
        acc += __shfl_xor(acc, 16, 64);
        acc += __shfl_xor(acc, 32, 64);

        if (lane < 8) {
            float logit = c7 ? fmaf(di, acc, b3s[c8]) : -1e30f;
            float m = logit;
            m = fmaxf(m, __shfl_xor(m, 1, 8));
            m = fmaxf(m, __shfl_xor(m, 2, 8));
            m = fmaxf(m, __shfl_xor(m, 4, 8));
            float e = c7 ? expf(logit - m) : 0.0f;
            float ssum = e;
            ssum += __shfl_xor(ssum, 1, 8);
            ssum += __shfl_xor(ssum, 2, 8);
            ssum += __shfl_xor(ssum, 4, 8);
            if (c7) out[dst * 7 + c8] = logit - m - logf(ssum);
        }
    }
}

extern "C" void kernel_launch(void* const* d_in, const int* in_sizes, int n_in,
                              void* d_out, int out_size, void* d_ws, size_t ws_size,
                              hipStream_t stream)
{
    const float* x  = (const float*)d_in[0];
    const float* W1 = (const float*)d_in[1];
    const float* b1 = (const float*)d_in[2];
    const float* W2 = (const float*)d_in[3];
    const float* b2 = (const float*)d_in[4];
    const float* W3 = (const float*)d_in[5];
    const float* b3 = (const float*)d_in[6];
    const int*   ei = (const int*)d_in[7];
    float* out = (float*)d_out;

    int N = in_sizes[0] / F_IN;
    int E = in_sizes[7] / 2;

    int*   bar    = (int*)d_ws;                          // 16 (zeroed by k_gemm)
    int*   cnt    = bar + 16;                            // N  (zeroed by k_gemm)
    int*   bucket = cnt + N;                             // N*BCAP
    float* g1     = (float*)(bucket + (size_t)N * BCAP); // 16N (raw x@W1)
    float* s2     = g1 + 16 * (size_t)N;                 // 16N
    float* s3     = s2 + 16 * (size_t)N;                 // 7N

    // node 1: gemm (+ zero bar/cnt); 16 rows per 512-thread block
    int nbG = (N + 15) / 16;
    k_gemm<<<nbG, 512, 0, stream>>>(x, W1, bar, N + 16, g1, N);

    // node 2: persistent cooperative graph pipeline at full occupancy
    int dev = 0, numCU = 256, occ = 8;
    hipGetDevice(&dev);
    hipDeviceProp_t props;
    if (hipGetDeviceProperties(&props, dev) == hipSuccess) numCU = props.multiProcessorCount;
    if (hipOccupancyMaxActiveBlocksPerMultiprocessor(&occ, k_graph, 256, 0) != hipSuccess || occ < 1)
        occ = 1;
    int grid = numCU * occ;

    k_graph<<<grid, 256, 0, stream>>>(ei, cnt, bucket, g1, W2, b1, W3, b2, b3,
                                      s2, s3, out, bar, N, E);
}

// Round 10
// 567.435 us; speedup vs baseline: 1.9534x; 1.9534x over previous
//
#include <hip/hip_runtime.h>
#include <hip/hip_fp16.h>

#define F_IN 1433
#define BCAP 96        // bucket capacity; deg ~ Poisson(32), P(>96) ~ 1e-18
#define KSTR 1480      // LDS Wt row stride in halfs: 740 dwords % 32 = 4 -> 2-way max

// edge_index int32: src = ei[0:E], dst = ei[E:2E]

typedef _Float16 f16x8 __attribute__((ext_vector_type(8)));
typedef float    f32x4 __attribute__((ext_vector_type(4)));

__global__ __launch_bounds__(256) void k_zero(int* __restrict__ p, int n) {
    int i = blockIdx.x * 256 + threadIdx.x;
    if (i < n) p[i] = 0;
}

// histogram + bucket scatter in one pass
__global__ __launch_bounds__(256) void k_scatter(const int* __restrict__ ei,
    int* cnt, int* bucket, int E, int N)
{
    int e = blockIdx.x * 256 + threadIdx.x;
    if (e < E) {
        int s = ei[e], d = ei[E + e];
        if ((unsigned)s < (unsigned)N && (unsigned)d < (unsigned)N) {
            int slot = atomicAdd(&cnt[d], 1);
            if (slot < BCAP) bucket[(size_t)d * BCAP + slot] = s;
        }
    }
}

// ---------------- layer-1 GEMM via MFMA: s1 = rsqrt(cnt+1) * (x @ W1) ----------------
// One wave per 16-row tile; K in chunks of 32 via v_mfma_f32_16x16x32_f16.
// A row / B col = lane&15; k-slot = (lane>>4)*8 + j (same bijection for A and B,
// so the result is layout-permutation-invariant). C/D: col=lane&15, row=(lane>>4)*4+reg.
__global__ __launch_bounds__(256) void k_gemm(
    const float* __restrict__ x, const float* __restrict__ W1,
    const int* __restrict__ cnt, float* __restrict__ s, int N)
{
    __shared__ _Float16 wt[16 * KSTR];   // Wt[c][k], zero-padded to 1472; 47360 B
    int tid = threadIdx.x;
    for (int i = tid; i < 16 * 1472; i += 256) {
        int c = i & 15, k = i >> 4;
        float v = (k < F_IN) ? W1[k * 16 + c] : 0.0f;
        wt[c * KSTR + k] = (_Float16)v;
    }
    __syncthreads();

    int wv = tid >> 6, lane = tid & 63;
    int ntiles = (N + 15) >> 4;
    int tile = blockIdx.x * 4 + wv;
    if (tile >= ntiles) return;

    int rc = lane & 15;          // A-row within tile, and B/D column
    int g  = lane >> 4;          // k-group
    int row = tile * 16 + rc;
    const float* xr = x + (size_t)((row < N) ? row : (N - 1)) * F_IN;
    const _Float16* wrow = wt + rc * KSTR;

    struct __attribute__((packed, aligned(4))) f4u { float f[4]; };

    f32x4 acc = {0.0f, 0.0f, 0.0f, 0.0f};
    int kb = g * 8;

    #pragma unroll 2
    for (int ch = 0; ch < 44; ++ch) {       // full chunks: k0 = ch*32 + g*8
        int k0 = ch * 32 + kb;
        f4u xa = *(const f4u*)&xr[k0];
        f4u xb = *(const f4u*)&xr[k0 + 4];
        f16x8 av, bv;
        bv = *(const f16x8*)&wrow[k0];      // 16B-aligned: (rc*KSTR + k0)*2 % 16 == 0
        #pragma unroll
        for (int j = 0; j < 4; ++j) {
            av[j]     = (_Float16)xa.f[j];
            av[j + 4] = (_Float16)xb.f[j];
        }
        acc = __builtin_amdgcn_mfma_f32_16x16x32_f16(av, bv, acc, 0, 0, 0);
    }
    {   // tail chunk: k0 = 1408 + g*8, elements k >= F_IN are zero (guarded)
        int k0 = 1408 + kb;
        f16x8 av, bv;
        bv = *(const f16x8*)&wrow[k0];      // LDS zero-padded
        #pragma unroll
        for (int j = 0; j < 8; ++j) {
            int k = k0 + j;
            av[j] = (_Float16)((k < F_IN) ? xr[k] : 0.0f);
        }
        acc = __builtin_amdgcn_mfma_f32_16x16x32_f16(av, bv, acc, 0, 0, 0);
    }

    #pragma unroll
    for (int r = 0; r < 4; ++r) {
        int grow = tile * 16 + g * 4 + r;   // C/D: row = (lane>>4)*4 + reg
        if (grow < N) {
            float di = rsqrtf((float)cnt[grow] + 1.0f);
            s[grow * 16 + rc] = acc[r] * di;
        }
    }
}

// ------- aggA: conv1-agg + b1 + relu + @W2 + dinv  (s1[16] -> s2[16]) -------
// one wave per dst; bucket row preloaded to regs, src via shfl; 4-way MLP gather
__global__ __launch_bounds__(256) void k_aggA(
    const int* __restrict__ cnt, const int* __restrict__ bucket,
    const float* __restrict__ sin, const float* __restrict__ W,
    const float* __restrict__ bias, float* __restrict__ sout, int N)
{
    __shared__ float w[256], bs[16];
    int tid = threadIdx.x;
    w[tid] = W[tid];
    if (tid < 16) bs[tid] = bias[tid];
    __syncthreads();

    int wave = tid >> 6, lane = tid & 63;
    int dst = blockIdx.x * 4 + wave;
    if (dst >= N) return;
    int g = lane >> 4, c = lane & 15;
    int deg = min(cnt[dst], BCAP);
    const int* bk = bucket + (size_t)dst * BCAP;

    int e0 = (lane < deg)      ? bk[lane]      : 0;
    int e1 = (64 + lane < deg) ? bk[64 + lane] : 0;

    float acc = (g == 0) ? sin[dst * 16 + c] : 0.0f;     // self-loop
    for (int base = 0; base < deg; base += 16) {
        int j0 = base + g, j1 = j0 + 4, j2 = j0 + 8, j3 = j0 + 12;
        int sa0 = __shfl(e0, j0 & 63, 64), sb0 = __shfl(e1, j0 & 63, 64);
        int sa1 = __shfl(e0, j1 & 63, 64), sb1 = __shfl(e1, j1 & 63, 64);
        int sa2 = __shfl(e0, j2 & 63, 64), sb2 = __shfl(e1, j2 & 63, 64);
        int sa3 = __shfl(e0, j3 & 63, 64), sb3 = __shfl(e1, j3 & 63, 64);
        int s0 = (j0 < 64) ? sa0 : sb0;
        int s1 = (j1 < 64) ? sa1 : sb1;
        int s2 = (j2 < 64) ? sa2 : sb2;
        int s3 = (j3 < 64) ? sa3 : sb3;
        float v0 = (j0 < deg) ? sin[s0 * 16 + c] : 0.0f;
        float v1 = (j1 < deg) ? sin[s1 * 16 + c] : 0.0f;
        float v2 = (j2 < deg) ? sin[s2 * 16 + c] : 0.0f;
        float v3 = (j3 < deg) ? sin[s3 * 16 + c] : 0.0f;
        acc += (v0 + v1) + (v2 + v3);
    }
    acc += __shfl_xor(acc, 16, 64);
    acc += __shfl_xor(acc, 32, 64);

    float di = rsqrtf((float)cnt[dst] + 1.0f);
    float h = fmaxf(fmaf(di, acc, bs[c]), 0.0f);
    float t = 0.0f;
    #pragma unroll
    for (int k = 0; k < 16; ++k)
        t = fmaf(__shfl(h, k, 16), w[k * 16 + c], t);
    if (lane < 16) sout[dst * 16 + c] = di * t;
}

// ------- aggB: conv2-agg + b2 + relu + @W3 + dinv  (s2[16] -> s3[7]) -------
__global__ __launch_bounds__(256) void k_aggB(
    const int* __restrict__ cnt, const int* __restrict__ bucket,
    const float* __restrict__ sin, const float* __restrict__ W,
    const float* __restrict__ bias, float* __restrict__ sout, int N)
{
    __shared__ float w[112], bs[16];
    int tid = threadIdx.x;
    if (tid < 112) w[tid] = W[tid];
    if (tid < 16) bs[tid] = bias[tid];
    __syncthreads();

    int wave = tid >> 6, lane = tid & 63;
    int dst = blockIdx.x * 4 + wave;
    if (dst >= N) return;
    int g = lane >> 4, c = lane & 15;
    int deg = min(cnt[dst], BCAP);
    const int* bk = bucket + (size_t)dst * BCAP;

    int e0 = (lane < deg)      ? bk[lane]      : 0;
    int e1 = (64 + lane < deg) ? bk[64 + lane] : 0;

    float acc = (g == 0) ? sin[dst * 16 + c] : 0.0f;
    for (int base = 0; base < deg; base += 16) {
        int j0 = base + g, j1 = j0 + 4, j2 = j0 + 8, j3 = j0 + 12;
        int sa0 = __shfl(e0, j0 & 63, 64), sb0 = __shfl(e1, j0 & 63, 64);
        int sa1 = __shfl(e0, j1 & 63, 64), sb1 = __shfl(e1, j1 & 63, 64);
        int sa2 = __shfl(e0, j2 & 63, 64), sb2 = __shfl(e1, j2 & 63, 64);
        int sa3 = __shfl(e0, j3 & 63, 64), sb3 = __shfl(e1, j3 & 63, 64);
        int s0 = (j0 < 64) ? sa0 : sb0;
        int s1 = (j1 < 64) ? sa1 : sb1;
        int s2 = (j2 < 64) ? sa2 : sb2;
        int s3 = (j3 < 64) ? sa3 : sb3;
        float v0 = (j0 < deg) ? sin[s0 * 16 + c] : 0.0f;
        float v1 = (j1 < deg) ? sin[s1 * 16 + c] : 0.0f;
        float v2 = (j2 < deg) ? sin[s2 * 16 + c] : 0.0f;
        float v3 = (j3 < deg) ? sin[s3 * 16 + c] : 0.0f;
        acc += (v0 + v1) + (v2 + v3);
    }
    acc += __shfl_xor(acc, 16, 64);
    acc += __shfl_xor(acc, 32, 64);

    float di = rsqrtf((float)cnt[dst] + 1.0f);
    float h = fmaxf(fmaf(di, acc, bs[c]), 0.0f);
    int cc = (c < 7) ? c : 0;
    float t = 0.0f;
    #pragma unroll
    for (int k = 0; k < 16; ++k)
        t = fmaf(__shfl(h, k, 16), w[k * 7 + cc], t);
    if (lane < 7) sout[dst * 7 + c] = di * t;
}

// ------- aggC: conv3-agg + b3 + log_softmax  (s3[7] -> out[7]) -------
__global__ __launch_bounds__(256) void k_aggC(
    const int* __restrict__ cnt, const int* __restrict__ bucket,
    const float* __restrict__ sin, const float* __restrict__ bias,
    float* __restrict__ out, int N)
{
    __shared__ float bs[8];
    int tid = threadIdx.x;
    if (tid < 7) bs[tid] = bias[tid];
    if (tid == 7) bs[7] = 0.0f;
    __syncthreads();

    int wave = tid >> 6, lane = tid & 63;
    int dst = blockIdx.x * 4 + wave;
    if (dst >= N) return;
    int g = lane >> 3, c8 = lane & 7;
    bool c7 = (c8 < 7);
    int cc = c7 ? c8 : 0;
    int deg = min(cnt[dst], BCAP);
    const int* bk = bucket + (size_t)dst * BCAP;

    int e0 = (lane < deg)      ? bk[lane]      : 0;
    int e1 = (64 + lane < deg) ? bk[64 + lane] : 0;

    float acc = (g == 0 && c7) ? sin[dst * 7 + c8] : 0.0f;
    for (int base = 0; base < deg; base += 32) {
        int j0 = base + g, j1 = j0 + 8, j2 = j0 + 16, j3 = j0 + 24;
        int sa0 = __shfl(e0, j0 & 63, 64), sb0 = __shfl(e1, j0 & 63, 64);
        int sa1 = __shfl(e0, j1 & 63, 64), sb1 = __shfl(e1, j1 & 63, 64);
        int sa2 = __shfl(e0, j2 & 63, 64), sb2 = __shfl(e1, j2 & 63, 64);
        int sa3 = __shfl(e0, j3 & 63, 64), sb3 = __shfl(e1, j3 & 63, 64);
        int s0 = (j0 < 64) ? sa0 : sb0;
        int s1 = (j1 < 64) ? sa1 : sb1;
        int s2 = (j2 < 64) ? sa2 : sb2;
        int s3 = (j3 < 64) ? sa3 : sb3;
        float v0 = (j0 < deg && c7) ? sin[s0 * 7 + cc] : 0.0f;
        float v1 = (j1 < deg && c7) ? sin[s1 * 7 + cc] : 0.0f;
        float v2 = (j2 < deg && c7) ? sin[s2 * 7 + cc] : 0.0f;
        float v3 = (j3 < deg && c7) ? sin[s3 * 7 + cc] : 0.0f;
        acc += (v0 + v1) + (v2 + v3);
    }
    acc += __shfl_xor(acc, 8, 64);
    acc += __shfl_xor(acc, 16, 64);
    acc += __shfl_xor(acc, 32, 64);

    if (lane < 8) {
        float di = rsqrtf((float)cnt[dst] + 1.0f);
        float logit = c7 ? fmaf(di, acc, bs[c8]) : -1e30f;
        float m = logit;
        m = fmaxf(m, __shfl_xor(m, 1, 8));
        m = fmaxf(m, __shfl_xor(m, 2, 8));
        m = fmaxf(m, __shfl_xor(m, 4, 8));
        float e = c7 ? expf(logit - m) : 0.0f;
        float ssum = e;
        ssum += __shfl_xor(ssum, 1, 8);
        ssum += __shfl_xor(ssum, 2, 8);
        ssum += __shfl_xor(ssum, 4, 8);
        if (c7) out[dst * 7 + c8] = logit - m - logf(ssum);
    }
}

extern "C" void kernel_launch(void* const* d_in, const int* in_sizes, int n_in,
                              void* d_out, int out_size, void* d_ws, size_t ws_size,
                              hipStream_t stream)
{
    const float* x  = (const float*)d_in[0];
    const float* W1 = (const float*)d_in[1];
    const float* b1 = (const float*)d_in[2];
    const float* W2 = (const float*)d_in[3];
    const float* b2 = (const float*)d_in[4];
    const float* W3 = (const float*)d_in[5];
    const float* b3 = (const float*)d_in[6];
    const int*   ei = (const int*)d_in[7];
    float* out = (float*)d_out;

    int N = in_sizes[0] / F_IN;
    int E = in_sizes[7] / 2;

    int*   cnt    = (int*)d_ws;                          // N
    int*   bucket = cnt + N;                             // N*BCAP
    float* s1     = (float*)(bucket + (size_t)N * BCAP); // 16N
    float* s2     = s1 + 16 * (size_t)N;                 // 16N
    float* s3     = s2 + 16 * (size_t)N;                 // 7N

    int nbN = (N + 255) / 256;
    int nbE = (E + 255) / 256;
    int nb4 = (N + 3) / 4;
    int ntiles = (N + 15) / 16;
    int nbG = (ntiles + 3) / 4;

    k_zero   <<<nbN, 256, 0, stream>>>(cnt, N);
    k_scatter<<<nbE, 256, 0, stream>>>(ei, cnt, bucket, E, N);
    k_gemm   <<<nbG, 256, 0, stream>>>(x, W1, cnt, s1, N);
    k_aggA   <<<nb4, 256, 0, stream>>>(cnt, bucket, s1, W2, b1, s2, N);
    k_aggB   <<<nb4, 256, 0, stream>>>(cnt, bucket, s2, W3, b2, s3, N);
    k_aggC   <<<nb4, 256, 0, stream>>>(cnt, bucket, s3, b3, out, N);
}